// Round 5
// baseline (82.947 us; speedup 1.0000x reference)
//
#include <hip/hip_runtime.h>

// spatial_adaptive_operator: B=4, H=W=128, N=16384, C=128, P=4
// d_in: [0]=x (B,N,C) f32, [1]=deltaA (B,N,C) f32, [2]=H, [3]=W, [4]=Wo (8,C) f32, [5]=bo (8,) f32
// d_out: out (B,N,C) f32  ++  sampling_locations (B,N,1,1,P,2) f32
//
// R4: split into GEMV pass (writes locs) + gather pass (reads locs) to break
// the per-wave serial chain  x-row load -> reduce -> gathers.

#define HW_ 128
#define CC_ 128
#define PP_ 4
#define NN_ (HW_ * HW_)

typedef float f32x4 __attribute__((ext_vector_type(4)));

// ---- Pass A: off = x . Wo^T + bo ; locs = ref + off/128 ----------------
__global__ __launch_bounds__(256) void sao_gemv(
    const float* __restrict__ x,
    const float* __restrict__ Wo,
    const float* __restrict__ bo,
    float* __restrict__ locs)
{
    const int wid = blockIdx.x * 4 + (threadIdx.x >> 6);  // point id
    const int lane = threadIdx.x & 63;
    const int o = lane & 7;        // output index
    const int chunk = lane >> 3;   // 16-channel chunk

    const float* xr = x + (size_t)wid * CC_ + chunk * 16;
    const float* wr = Wo + o * CC_ + chunk * 16;
    float partial = 0.0f;
#pragma unroll
    for (int j = 0; j < 4; ++j) {
        const float4 xv = *(const float4*)(xr + 4 * j);
        const float4 wv = *(const float4*)(wr + 4 * j);
        partial += xv.x * wv.x + xv.y * wv.y + xv.z * wv.z + xv.w * wv.w;
    }
    partial += __shfl_xor(partial, 8);
    partial += __shfl_xor(partial, 16);
    partial += __shfl_xor(partial, 32);

    if (lane < 8) {
        const int n = wid & (NN_ - 1);
        const int ix = n & (HW_ - 1);
        const int iy = n >> 7;
        const float refx = (ix + 0.5f) * (1.0f / HW_);
        const float refy = (iy + 0.5f) * (1.0f / HW_);
        const float ref = (o & 1) ? refy : refx;
        const float off = partial + bo[o];
        __builtin_nontemporal_store(ref + off * (1.0f / HW_),
                                    locs + (size_t)wid * 8 + o);
    }
}

// ---- Pass B: bilinear gather + aggregate -------------------------------
__global__ __launch_bounds__(256) void sao_gather(
    const float* __restrict__ x,
    const float* __restrict__ dA,
    const float* __restrict__ locs,
    float* __restrict__ out)
{
    const int lane = threadIdx.x & 63;
    const int h = lane >> 5;           // which of the wave's 2 points
    const int s = lane & 31;           // sub-lane within the point
    const int wv = threadIdx.x >> 6;   // wave index in block (0..3)

    // bijective XCD-chunked swizzle (contiguous image band per XCD's L2)
    const int nblk = gridDim.x;
    const int q = nblk >> 3, r = nblk & 7;
    const int xcd = blockIdx.x & 7;
    const int work = (xcd < r ? xcd * (q + 1) : r * (q + 1) + (xcd - r) * q)
                     + (blockIdx.x >> 3);

    const int pt = work * 8 + wv * 2 + h;   // point id in [0, B*N)
    const int b = pt >> 14;

    const size_t rowstart = (size_t)pt * CC_;

    // this lane's 4 channels of deltaA
    const float4 d4 = *(const float4*)(dA + rowstart + s * 4);

    // sampling locations for this point (uniform across the half-wave)
    const f32x4 lo0 = *(const f32x4*)(locs + (size_t)pt * 8);
    const f32x4 lo1 = *(const f32x4*)(locs + (size_t)pt * 8 + 4);
    const float lx[4] = {lo0.x, lo0.z, lo1.x, lo1.z};
    const float ly[4] = {lo0.y, lo0.w, lo1.y, lo1.w};

    const size_t bbase = (size_t)b * (size_t)(NN_ * CC_) + s * 4;

    float4 acc = make_float4(0.f, 0.f, 0.f, 0.f);
#pragma unroll
    for (int p = 0; p < PP_; ++p) {
        // bit-exact mirror of reference arithmetic (f32)
        const float gx = 2.0f * lx[p] - 1.0f;
        const float gy = 2.0f * ly[p] - 1.0f;
        const float xp = ((gx + 1.0f) * (float)HW_ - 1.0f) * 0.5f;
        const float yp = ((gy + 1.0f) * (float)HW_ - 1.0f) * 0.5f;
        const float x0f = floorf(xp), y0f = floorf(yp);
        const float wx1 = xp - x0f, wy1 = yp - y0f;
        const float wx0 = 1.0f - wx1, wy0 = 1.0f - wy1;
        const int ix0 = (int)x0f, iy0 = (int)y0f;

        float4 feat = make_float4(0.f, 0.f, 0.f, 0.f);
        float4 wt = make_float4(0.f, 0.f, 0.f, 0.f);
#pragma unroll
        for (int k = 0; k < 4; ++k) {
            const int cx = ix0 + (k & 1);
            const int cy = iy0 + (k >> 1);
            const bool valid = (cx >= 0) & (cx < HW_) & (cy >= 0) & (cy < HW_);
            float w = ((k & 1) ? wx1 : wx0) * ((k >> 1) ? wy1 : wy0);
            w = valid ? w : 0.0f;
            const int pix = min(max(cy, 0), HW_ - 1) * HW_ + min(max(cx, 0), HW_ - 1);
            const size_t cb = bbase + (size_t)pix * CC_;
            const float4 xv = *(const float4*)(x + cb);
            const float4 dv = *(const float4*)(dA + cb);
            feat.x = fmaf(w, xv.x, feat.x);
            feat.y = fmaf(w, xv.y, feat.y);
            feat.z = fmaf(w, xv.z, feat.z);
            feat.w = fmaf(w, xv.w, feat.w);
            wt.x = fmaf(w, dv.x, wt.x);
            wt.y = fmaf(w, dv.y, wt.y);
            wt.z = fmaf(w, dv.z, wt.z);
            wt.w = fmaf(w, dv.w, wt.w);
        }
        acc.x = fmaf(feat.x, wt.x - d4.x, acc.x);
        acc.y = fmaf(feat.y, wt.y - d4.y, acc.y);
        acc.z = fmaf(feat.z, wt.z - d4.z, acc.z);
        acc.w = fmaf(feat.w, wt.w - d4.w, acc.w);
    }

    f32x4 res;
    res.x = acc.x * 0.25f;
    res.y = acc.y * 0.25f;
    res.z = acc.z * 0.25f;
    res.w = acc.w * 0.25f;
    __builtin_nontemporal_store(res, (f32x4*)(out + rowstart + s * 4));
}

extern "C" void kernel_launch(void* const* d_in, const int* in_sizes, int n_in,
                              void* d_out, int out_size, void* d_ws, size_t ws_size,
                              hipStream_t stream) {
    const float* x = (const float*)d_in[0];
    const float* dA = (const float*)d_in[1];
    const float* Wo = (const float*)d_in[4];
    const float* bo = (const float*)d_in[5];
    float* out = (float*)d_out;

    const int points = in_sizes[0] / CC_;               // B*N = 65536
    float* locs = out + (size_t)points * CC_;           // second tuple output

    sao_gemv<<<points / 4, 256, 0, stream>>>(x, Wo, bo, locs);
    sao_gather<<<points / 8, 256, 0, stream>>>(x, dA, locs, out);
}

// Round 6
// 72.290 us; speedup vs baseline: 1.1474x; 1.1474x over previous
//
#include <hip/hip_runtime.h>

// spatial_adaptive_operator: B=4, H=W=128, N=16384, C=128, P=4
// d_in: [0]=x (B,N,C) f32, [1]=deltaA (B,N,C) f32, [2]=H, [3]=W, [4]=Wo (8,C) f32, [5]=bo (8,) f32
// d_out: out (B,N,C) f32  ++  sampling_locations (B,N,1,1,P,2) f32
//
// R5: fused again (R3 base), gather loop restructured for max MLP:
// all 16 corner offsets/weights precomputed, 16 x-gathers batch-issued,
// then 16 dA-gathers batch-issued. launch_bounds(256,4) -> <=128 VGPR.

#define HW_ 128
#define CC_ 128
#define PP_ 4
#define NN_ (HW_ * HW_)

typedef float f32x4 __attribute__((ext_vector_type(4)));

__global__ __launch_bounds__(256, 4) void sao_kernel(
    const float* __restrict__ x,
    const float* __restrict__ dA,
    const float* __restrict__ Wo,
    const float* __restrict__ bo,
    float* __restrict__ out,
    float* __restrict__ locs)
{
    const int lane = threadIdx.x & 63;
    const int h = lane >> 5;           // which of the wave's 2 points
    const int s = lane & 31;           // sub-lane within the point
    const int wv = threadIdx.x >> 6;   // wave index in block (0..3)

    // bijective XCD-chunked swizzle (contiguous image band per XCD's L2)
    const int nblk = gridDim.x;
    const int q = nblk >> 3, r = nblk & 7;
    const int xcd = blockIdx.x & 7;
    const int work = (xcd < r ? xcd * (q + 1) : r * (q + 1) + (xcd - r) * q)
                     + (blockIdx.x >> 3);

    const int pt = work * 8 + wv * 2 + h;   // point id in [0, B*N)
    const int b = pt >> 14;
    const int n = pt & (NN_ - 1);
    const int ix = n & (HW_ - 1);
    const int iy = n >> 7;

    const size_t rowstart = (size_t)pt * CC_;

    // this lane's 4 channels of deltaA (early, independent)
    const float4 d4 = *(const float4*)(dA + rowstart + s * 4);

    // ---- GEMV: off[o] = dot(x_row, Wo[o]) + bo[o], per half-wave ----
    const int o = s & 7;
    const int chunk = s >> 3;
    const float* xr = x + rowstart + chunk * 32;
    const float* wr = Wo + o * CC_ + chunk * 32;
    float partial = 0.0f;
#pragma unroll
    for (int j = 0; j < 8; ++j) {
        const float4 xv = *(const float4*)(xr + 4 * j);
        const float4 wvv = *(const float4*)(wr + 4 * j);
        partial += xv.x * wvv.x + xv.y * wvv.y + xv.z * wvv.z + xv.w * wvv.w;
    }
    partial += __shfl_xor(partial, 8);
    partial += __shfl_xor(partial, 16);
    const float offv = partial + bo[o];   // lanes s=0..7 hold off[0..7]

    const float refx = (ix + 0.5f) * (1.0f / HW_);
    const float refy = (iy + 0.5f) * (1.0f / HW_);

    if (s < 8) {
        const float ref = (o & 1) ? refy : refx;
        __builtin_nontemporal_store(ref + offv * (1.0f / HW_),
                                    locs + (size_t)pt * 8 + o);
    }

    // broadcast the 8 offsets within each half-wave
    float offs[8];
#pragma unroll
    for (int oo = 0; oo < 8; ++oo)
        offs[oo] = __shfl(offv, oo, 32);

    // ---- precompute all 16 corner element-offsets + weights ----
    int eoff[PP_][4];
    float wgt[PP_][4];
#pragma unroll
    for (int p = 0; p < PP_; ++p) {
        // bit-exact mirror of reference arithmetic (f32)
        const float locx = refx + offs[2 * p] * (1.0f / HW_);
        const float locy = refy + offs[2 * p + 1] * (1.0f / HW_);
        const float gx = 2.0f * locx - 1.0f;
        const float gy = 2.0f * locy - 1.0f;
        const float xp = ((gx + 1.0f) * (float)HW_ - 1.0f) * 0.5f;
        const float yp = ((gy + 1.0f) * (float)HW_ - 1.0f) * 0.5f;
        const float x0f = floorf(xp), y0f = floorf(yp);
        const float wx1 = xp - x0f, wy1 = yp - y0f;
        const float wx0 = 1.0f - wx1, wy0 = 1.0f - wy1;
        const int ix0 = (int)x0f, iy0 = (int)y0f;
#pragma unroll
        for (int k = 0; k < 4; ++k) {
            const int cx = ix0 + (k & 1);
            const int cy = iy0 + (k >> 1);
            const bool valid = (cx >= 0) & (cx < HW_) & (cy >= 0) & (cy < HW_);
            float w = ((k & 1) ? wx1 : wx0) * ((k >> 1) ? wy1 : wy0);
            wgt[p][k] = valid ? w : 0.0f;
            const int pix = min(max(cy, 0), HW_ - 1) * HW_ + min(max(cx, 0), HW_ - 1);
            eoff[p][k] = (b * NN_ + pix) * CC_ + s * 4;   // fits in int (<34M)
        }
    }

    // ---- batch-issue all 16 x gathers (MLP ~16), reduce to feat[p] ----
    f32x4 xg[PP_][4];
#pragma unroll
    for (int p = 0; p < PP_; ++p)
#pragma unroll
        for (int k = 0; k < 4; ++k)
            xg[p][k] = *(const f32x4*)(x + eoff[p][k]);

    f32x4 feat[PP_];
#pragma unroll
    for (int p = 0; p < PP_; ++p) {
        f32x4 f;
        f.x = f.y = f.z = f.w = 0.0f;
#pragma unroll
        for (int k = 0; k < 4; ++k) {
            const float w = wgt[p][k];
            f.x = fmaf(w, xg[p][k].x, f.x);
            f.y = fmaf(w, xg[p][k].y, f.y);
            f.z = fmaf(w, xg[p][k].z, f.z);
            f.w = fmaf(w, xg[p][k].w, f.w);
        }
        feat[p] = f;
    }

    // ---- batch-issue all 16 dA gathers, combine ----
    f32x4 dg[PP_][4];
#pragma unroll
    for (int p = 0; p < PP_; ++p)
#pragma unroll
        for (int k = 0; k < 4; ++k)
            dg[p][k] = *(const f32x4*)(dA + eoff[p][k]);

    f32x4 acc;
    acc.x = acc.y = acc.z = acc.w = 0.0f;
#pragma unroll
    for (int p = 0; p < PP_; ++p) {
        f32x4 wt;
        wt.x = wt.y = wt.z = wt.w = 0.0f;
#pragma unroll
        for (int k = 0; k < 4; ++k) {
            const float w = wgt[p][k];
            wt.x = fmaf(w, dg[p][k].x, wt.x);
            wt.y = fmaf(w, dg[p][k].y, wt.y);
            wt.z = fmaf(w, dg[p][k].z, wt.z);
            wt.w = fmaf(w, dg[p][k].w, wt.w);
        }
        acc.x = fmaf(feat[p].x, wt.x - d4.x, acc.x);
        acc.y = fmaf(feat[p].y, wt.y - d4.y, acc.y);
        acc.z = fmaf(feat[p].z, wt.z - d4.z, acc.z);
        acc.w = fmaf(feat[p].w, wt.w - d4.w, acc.w);
    }

    f32x4 res;
    res.x = acc.x * 0.25f;
    res.y = acc.y * 0.25f;
    res.z = acc.z * 0.25f;
    res.w = acc.w * 0.25f;
    __builtin_nontemporal_store(res, (f32x4*)(out + rowstart + s * 4));
}

extern "C" void kernel_launch(void* const* d_in, const int* in_sizes, int n_in,
                              void* d_out, int out_size, void* d_ws, size_t ws_size,
                              hipStream_t stream) {
    const float* x = (const float*)d_in[0];
    const float* dA = (const float*)d_in[1];
    const float* Wo = (const float*)d_in[4];
    const float* bo = (const float*)d_in[5];
    float* out = (float*)d_out;

    const int points = in_sizes[0] / CC_;               // B*N = 65536
    float* locs = out + (size_t)points * CC_;           // second tuple output

    const int blocks = points / 8;                      // 8 points per 256-thr block
    sao_kernel<<<blocks, 256, 0, stream>>>(x, dA, Wo, bo, out, locs);
}

// Round 7
// 68.609 us; speedup vs baseline: 1.2090x; 1.0536x over previous
//
#include <hip/hip_runtime.h>

// spatial_adaptive_operator: B=4, H=W=128, N=16384, C=128, P=4
// d_in: [0]=x (B,N,C) f32, [1]=deltaA (B,N,C) f32, [2]=H, [3]=W, [4]=Wo (8,C) f32, [5]=bo (8,) f32
// d_out: out (B,N,C) f32  ++  sampling_locations (B,N,1,1,P,2) f32
//
// R6: two-pass, fp16-packed gather source.
//  Pass A: GEMV -> locs;  pack x||dA interleaved fp16 into d_ws (32MB).
//  Pass B: bilinear gathers from packed (512B/corner instead of 1KB) -> out.
// Theory: R4/R5 showed L2-BW-bound on gather bytes (~19TB/s sustained);
// halving gathered bytes should halve pass-B time.

#define HW_ 128
#define CC_ 128
#define PP_ 4
#define NN_ (HW_ * HW_)

typedef float f32x4 __attribute__((ext_vector_type(4)));
typedef _Float16 f16x8 __attribute__((ext_vector_type(8)));

// ---- Pass A: GEMV -> locs ; pack fp16 x||dA -------------------------------
__global__ __launch_bounds__(256) void sao_pack(
    const float* __restrict__ x,
    const float* __restrict__ dA,
    const float* __restrict__ Wo,
    const float* __restrict__ bo,
    float* __restrict__ locs,
    _Float16* __restrict__ packed)
{
    const int lane = threadIdx.x & 63;
    const int h = lane >> 5;          // which of the wave's 2 points
    const int s = lane & 31;          // sub-lane within the point
    const int wv = threadIdx.x >> 6;
    const int pt = blockIdx.x * 8 + wv * 2 + h;
    const int n = pt & (NN_ - 1);
    const int ix = n & (HW_ - 1);
    const int iy = n >> 7;
    const size_t rowstart = (size_t)pt * CC_;

    // pack: lane covers channels 4s..4s+3; layout per pixel:
    // 32 blocks of [x0 x1 x2 x3 d0 d1 d2 d3] fp16 (16B) -> 512B/pixel
    const float4 xo = *(const float4*)(x + rowstart + s * 4);
    const float4 dd = *(const float4*)(dA + rowstart + s * 4);
    f16x8 pk;
    pk[0] = (_Float16)xo.x; pk[1] = (_Float16)xo.y;
    pk[2] = (_Float16)xo.z; pk[3] = (_Float16)xo.w;
    pk[4] = (_Float16)dd.x; pk[5] = (_Float16)dd.y;
    pk[6] = (_Float16)dd.z; pk[7] = (_Float16)dd.w;
    *(f16x8*)(packed + (size_t)pt * 256 + s * 8) = pk;

    // GEMV: off[o] = dot(x_row, Wo[o]) + bo[o]; o=s&7, chunk=s>>3 (32 ch)
    const int o = s & 7;
    const int chunk = s >> 3;
    const float* xr = x + rowstart + chunk * 32;
    const float* wr = Wo + o * CC_ + chunk * 32;
    float partial = 0.0f;
#pragma unroll
    for (int j = 0; j < 8; ++j) {
        const float4 a = *(const float4*)(xr + 4 * j);
        const float4 w = *(const float4*)(wr + 4 * j);
        partial += a.x * w.x + a.y * w.y + a.z * w.z + a.w * w.w;
    }
    partial += __shfl_xor(partial, 8);
    partial += __shfl_xor(partial, 16);

    if (s < 8) {
        const float refx = (ix + 0.5f) * (1.0f / HW_);
        const float refy = (iy + 0.5f) * (1.0f / HW_);
        const float ref = (o & 1) ? refy : refx;
        locs[(size_t)pt * 8 + o] = ref + (partial + bo[o]) * (1.0f / HW_);
    }
}

// ---- Pass B: fp16 bilinear gather + aggregate ------------------------------
__global__ __launch_bounds__(256) void sao_gather(
    const _Float16* __restrict__ packed,
    const float* __restrict__ locs,
    float* __restrict__ out)
{
    const int lane = threadIdx.x & 63;
    const int h = lane >> 5;
    const int s = lane & 31;
    const int wv = threadIdx.x >> 6;

    // bijective XCD-chunked swizzle
    const int nblk = gridDim.x;
    const int q = nblk >> 3, r = nblk & 7;
    const int xcd = blockIdx.x & 7;
    const int work = (xcd < r ? xcd * (q + 1) : r * (q + 1) + (xcd - r) * q)
                     + (blockIdx.x >> 3);

    const int pt = work * 8 + wv * 2 + h;
    const int b = pt >> 14;
    const size_t rowstart = (size_t)pt * CC_;

    // sampling locations (uniform per half-wave)
    const f32x4 lo0 = *(const f32x4*)(locs + (size_t)pt * 8);
    const f32x4 lo1 = *(const f32x4*)(locs + (size_t)pt * 8 + 4);
    const float lx[4] = {lo0.x, lo0.z, lo1.x, lo1.z};
    const float ly[4] = {lo0.y, lo0.w, lo1.y, lo1.w};

    // own-row packed block: dA_own in elements 4..7
    const f16x8 own = *(const f16x8*)(packed + (size_t)pt * 256 + s * 8);

    // corner offsets + weights (bit-exact reference coord math)
    int eoff[PP_][4];
    float wgt[PP_][4];
#pragma unroll
    for (int p = 0; p < PP_; ++p) {
        const float gx = 2.0f * lx[p] - 1.0f;
        const float gy = 2.0f * ly[p] - 1.0f;
        const float xp = ((gx + 1.0f) * (float)HW_ - 1.0f) * 0.5f;
        const float yp = ((gy + 1.0f) * (float)HW_ - 1.0f) * 0.5f;
        const float x0f = floorf(xp), y0f = floorf(yp);
        const float wx1 = xp - x0f, wy1 = yp - y0f;
        const float wx0 = 1.0f - wx1, wy0 = 1.0f - wy1;
        const int ix0 = (int)x0f, iy0 = (int)y0f;
#pragma unroll
        for (int k = 0; k < 4; ++k) {
            const int cx = ix0 + (k & 1);
            const int cy = iy0 + (k >> 1);
            const bool valid = (cx >= 0) & (cx < HW_) & (cy >= 0) & (cy < HW_);
            float w = ((k & 1) ? wx1 : wx0) * ((k >> 1) ? wy1 : wy0);
            wgt[p][k] = valid ? w : 0.0f;
            const int pix = min(max(cy, 0), HW_ - 1) * HW_ + min(max(cx, 0), HW_ - 1);
            eoff[p][k] = pix * 256;            // fp16 element offset within batch
        }
    }

    const _Float16* pb = packed + (size_t)b * ((size_t)NN_ * 256) + s * 8;

    // gather + packed-fp16 accumulate: fw[p] = [feat ch0..3 | wt ch0..3]
    f16x8 fw[PP_];
#pragma unroll
    for (int p = 0; p < PP_; ++p) {
        f16x8 a0 = *(const f16x8*)(pb + eoff[p][0]);
        f16x8 a1 = *(const f16x8*)(pb + eoff[p][1]);
        f16x8 a2 = *(const f16x8*)(pb + eoff[p][2]);
        f16x8 a3 = *(const f16x8*)(pb + eoff[p][3]);
        fw[p] = a0 * (_Float16)wgt[p][0] + a1 * (_Float16)wgt[p][1]
              + a2 * (_Float16)wgt[p][2] + a3 * (_Float16)wgt[p][3];
    }

    // combine in f32: acc_c += feat_c * (wt_c - dA_own_c)
    f32x4 acc;
    acc.x = acc.y = acc.z = acc.w = 0.0f;
    const float d0 = (float)own[4], d1 = (float)own[5];
    const float d2 = (float)own[6], d3 = (float)own[7];
#pragma unroll
    for (int p = 0; p < PP_; ++p) {
        acc.x = fmaf((float)fw[p][0], (float)fw[p][4] - d0, acc.x);
        acc.y = fmaf((float)fw[p][1], (float)fw[p][5] - d1, acc.y);
        acc.z = fmaf((float)fw[p][2], (float)fw[p][6] - d2, acc.z);
        acc.w = fmaf((float)fw[p][3], (float)fw[p][7] - d3, acc.w);
    }

    f32x4 res;
    res.x = acc.x * 0.25f;
    res.y = acc.y * 0.25f;
    res.z = acc.z * 0.25f;
    res.w = acc.w * 0.25f;
    __builtin_nontemporal_store(res, (f32x4*)(out + rowstart + s * 4));
}

// ---- Fallback: fused f32 kernel (R5, known-good) if ws too small ----------
__global__ __launch_bounds__(256) void sao_fused(
    const float* __restrict__ x,
    const float* __restrict__ dA,
    const float* __restrict__ Wo,
    const float* __restrict__ bo,
    float* __restrict__ out,
    float* __restrict__ locs)
{
    const int lane = threadIdx.x & 63;
    const int h = lane >> 5;
    const int s = lane & 31;
    const int wv = threadIdx.x >> 6;
    const int nblk = gridDim.x;
    const int q = nblk >> 3, r = nblk & 7;
    const int xcd = blockIdx.x & 7;
    const int work = (xcd < r ? xcd * (q + 1) : r * (q + 1) + (xcd - r) * q)
                     + (blockIdx.x >> 3);
    const int pt = work * 8 + wv * 2 + h;
    const int b = pt >> 14;
    const int n = pt & (NN_ - 1);
    const int ix = n & (HW_ - 1);
    const int iy = n >> 7;
    const size_t rowstart = (size_t)pt * CC_;
    const float4 d4 = *(const float4*)(dA + rowstart + s * 4);
    const int o = s & 7;
    const int chunk = s >> 3;
    const float* xr = x + rowstart + chunk * 32;
    const float* wr = Wo + o * CC_ + chunk * 32;
    float partial = 0.0f;
#pragma unroll
    for (int j = 0; j < 8; ++j) {
        const float4 xv = *(const float4*)(xr + 4 * j);
        const float4 wvv = *(const float4*)(wr + 4 * j);
        partial += xv.x * wvv.x + xv.y * wvv.y + xv.z * wvv.z + xv.w * wvv.w;
    }
    partial += __shfl_xor(partial, 8);
    partial += __shfl_xor(partial, 16);
    const float offv = partial + bo[o];
    const float refx = (ix + 0.5f) * (1.0f / HW_);
    const float refy = (iy + 0.5f) * (1.0f / HW_);
    if (s < 8) {
        const float ref = (o & 1) ? refy : refx;
        locs[(size_t)pt * 8 + o] = ref + offv * (1.0f / HW_);
    }
    float offs[8];
#pragma unroll
    for (int oo = 0; oo < 8; ++oo)
        offs[oo] = __shfl(offv, oo, 32);
    const size_t bbase = (size_t)b * (size_t)(NN_ * CC_) + s * 4;
    float4 acc = make_float4(0.f, 0.f, 0.f, 0.f);
#pragma unroll
    for (int p = 0; p < PP_; ++p) {
        const float locx = refx + offs[2 * p] * (1.0f / HW_);
        const float locy = refy + offs[2 * p + 1] * (1.0f / HW_);
        const float gx = 2.0f * locx - 1.0f;
        const float gy = 2.0f * locy - 1.0f;
        const float xp = ((gx + 1.0f) * (float)HW_ - 1.0f) * 0.5f;
        const float yp = ((gy + 1.0f) * (float)HW_ - 1.0f) * 0.5f;
        const float x0f = floorf(xp), y0f = floorf(yp);
        const float wx1 = xp - x0f, wy1 = yp - y0f;
        const float wx0 = 1.0f - wx1, wy0 = 1.0f - wy1;
        const int ix0 = (int)x0f, iy0 = (int)y0f;
        float4 feat = make_float4(0.f, 0.f, 0.f, 0.f);
        float4 wt = make_float4(0.f, 0.f, 0.f, 0.f);
#pragma unroll
        for (int k = 0; k < 4; ++k) {
            const int cx = ix0 + (k & 1);
            const int cy = iy0 + (k >> 1);
            const bool valid = (cx >= 0) & (cx < HW_) & (cy >= 0) & (cy < HW_);
            float w = ((k & 1) ? wx1 : wx0) * ((k >> 1) ? wy1 : wy0);
            w = valid ? w : 0.0f;
            const int pix = min(max(cy, 0), HW_ - 1) * HW_ + min(max(cx, 0), HW_ - 1);
            const size_t cb = bbase + (size_t)pix * CC_;
            const float4 xv = *(const float4*)(x + cb);
            const float4 dv = *(const float4*)(dA + cb);
            feat.x = fmaf(w, xv.x, feat.x);
            feat.y = fmaf(w, xv.y, feat.y);
            feat.z = fmaf(w, xv.z, feat.z);
            feat.w = fmaf(w, xv.w, feat.w);
            wt.x = fmaf(w, dv.x, wt.x);
            wt.y = fmaf(w, dv.y, wt.y);
            wt.z = fmaf(w, dv.z, wt.z);
            wt.w = fmaf(w, dv.w, wt.w);
        }
        acc.x = fmaf(feat.x, wt.x - d4.x, acc.x);
        acc.y = fmaf(feat.y, wt.y - d4.y, acc.y);
        acc.z = fmaf(feat.z, wt.z - d4.z, acc.z);
        acc.w = fmaf(feat.w, wt.w - d4.w, acc.w);
    }
    f32x4 res;
    res.x = acc.x * 0.25f;
    res.y = acc.y * 0.25f;
    res.z = acc.z * 0.25f;
    res.w = acc.w * 0.25f;
    __builtin_nontemporal_store(res, (f32x4*)(out + rowstart + s * 4));
}

extern "C" void kernel_launch(void* const* d_in, const int* in_sizes, int n_in,
                              void* d_out, int out_size, void* d_ws, size_t ws_size,
                              hipStream_t stream) {
    const float* x = (const float*)d_in[0];
    const float* dA = (const float*)d_in[1];
    const float* Wo = (const float*)d_in[4];
    const float* bo = (const float*)d_in[5];
    float* out = (float*)d_out;

    const int points = in_sizes[0] / CC_;               // B*N = 65536
    float* locs = out + (size_t)points * CC_;           // second tuple output
    const int blocks = points / 8;

    const size_t need = (size_t)points * 256 * sizeof(_Float16);  // 32 MB
    if (ws_size >= need) {
        _Float16* packed = (_Float16*)d_ws;
        sao_pack<<<blocks, 256, 0, stream>>>(x, dA, Wo, bo, locs, packed);
        sao_gather<<<blocks, 256, 0, stream>>>(packed, locs, out);
    } else {
        sao_fused<<<blocks, 256, 0, stream>>>(x, dA, Wo, bo, out, locs);
    }
}

// Round 8
// 45.890 us; speedup vs baseline: 1.8075x; 1.4951x over previous
//
#include <hip/hip_runtime.h>

// spatial_adaptive_operator: B=4, H=W=128, N=16384, C=128, P=4
// d_in: [0]=x (B,N,C) f32, [1]=deltaA (B,N,C) f32, [2]=H, [3]=W, [4]=Wo (8,C) f32, [5]=bo (8,) f32
// d_out: out (B,N,C) f32  ++  sampling_locations (B,N,1,1,P,2) f32
//
// R7: pass A reworked — GEMV now reuses the pack-load float4 (no extra x
// reads): per-lane 8 partials from own 4 channels + 5-level butterfly.
// Pass B (fp16 gather, ~24us measured) unchanged from R6.

#define HW_ 128
#define CC_ 128
#define PP_ 4
#define NN_ (HW_ * HW_)

typedef float f32x4 __attribute__((ext_vector_type(4)));
typedef _Float16 f16x8 __attribute__((ext_vector_type(8)));

// ---- Pass A: pack fp16 x||dA ; GEMV via butterfly -> locs ------------------
__global__ __launch_bounds__(256) void sao_pack(
    const float* __restrict__ x,
    const float* __restrict__ dA,
    const float* __restrict__ Wo,
    const float* __restrict__ bo,
    float* __restrict__ locs,
    _Float16* __restrict__ packed)
{
    const int lane = threadIdx.x & 63;
    const int h = lane >> 5;          // which of the wave's 2 points
    const int s = lane & 31;          // sub-lane within the point
    const int wv = threadIdx.x >> 6;
    const int pt = blockIdx.x * 8 + wv * 2 + h;
    const size_t rowstart = (size_t)pt * CC_;

    // own 4 channels (single read of x serves BOTH pack and GEMV)
    const float4 xo = *(const float4*)(x + rowstart + s * 4);
    const float4 dd = *(const float4*)(dA + rowstart + s * 4);

    // Wo fragment: Wo[o][4s..4s+3], o=0..7  (4KB total -> L1-resident)
    float4 wf[8];
#pragma unroll
    for (int o = 0; o < 8; ++o)
        wf[o] = *(const float4*)(Wo + o * CC_ + s * 4);

    // pack: [x0..x3 d0..d3] fp16, 16B/lane -> 512B/pixel
    f16x8 pk;
    pk[0] = (_Float16)xo.x; pk[1] = (_Float16)xo.y;
    pk[2] = (_Float16)xo.z; pk[3] = (_Float16)xo.w;
    pk[4] = (_Float16)dd.x; pk[5] = (_Float16)dd.y;
    pk[6] = (_Float16)dd.z; pk[7] = (_Float16)dd.w;
    *(f16x8*)(packed + (size_t)pt * 256 + s * 8) = pk;

    // per-lane partials for all 8 outputs from own 4 channels
    float p[8];
#pragma unroll
    for (int o = 0; o < 8; ++o)
        p[o] = xo.x * wf[o].x + xo.y * wf[o].y + xo.z * wf[o].z + xo.w * wf[o].w;

    // butterfly sum across the 32-lane half (masks <32 never cross halves)
#pragma unroll
    for (int m = 1; m <= 16; m <<= 1) {
#pragma unroll
        for (int o = 0; o < 8; ++o)
            p[o] += __shfl_xor(p[o], m);
    }

    // lanes s<8 store locs element s (static-index select from p[])
    if (s < 8) {
        float off = 0.0f;
#pragma unroll
        for (int o = 0; o < 8; ++o)
            if (o == s) off = p[o];
        off += bo[s];
        const int n = pt & (NN_ - 1);
        const int ix = n & (HW_ - 1);
        const int iy = n >> 7;
        const float refx = (ix + 0.5f) * (1.0f / HW_);
        const float refy = (iy + 0.5f) * (1.0f / HW_);
        const float ref = (s & 1) ? refy : refx;
        locs[(size_t)pt * 8 + s] = ref + off * (1.0f / HW_);
    }
}

// ---- Pass B: fp16 bilinear gather + aggregate (R6, measured ~24us) ---------
__global__ __launch_bounds__(256) void sao_gather(
    const _Float16* __restrict__ packed,
    const float* __restrict__ locs,
    float* __restrict__ out)
{
    const int lane = threadIdx.x & 63;
    const int h = lane >> 5;
    const int s = lane & 31;
    const int wv = threadIdx.x >> 6;

    // bijective XCD-chunked swizzle
    const int nblk = gridDim.x;
    const int q = nblk >> 3, r = nblk & 7;
    const int xcd = blockIdx.x & 7;
    const int work = (xcd < r ? xcd * (q + 1) : r * (q + 1) + (xcd - r) * q)
                     + (blockIdx.x >> 3);

    const int pt = work * 8 + wv * 2 + h;
    const int b = pt >> 14;
    const size_t rowstart = (size_t)pt * CC_;

    // sampling locations (uniform per half-wave)
    const f32x4 lo0 = *(const f32x4*)(locs + (size_t)pt * 8);
    const f32x4 lo1 = *(const f32x4*)(locs + (size_t)pt * 8 + 4);
    const float lx[4] = {lo0.x, lo0.z, lo1.x, lo1.z};
    const float ly[4] = {lo0.y, lo0.w, lo1.y, lo1.w};

    // own-row packed block: dA_own in elements 4..7
    const f16x8 own = *(const f16x8*)(packed + (size_t)pt * 256 + s * 8);

    // corner offsets + weights (bit-exact reference coord math)
    int eoff[PP_][4];
    float wgt[PP_][4];
#pragma unroll
    for (int p = 0; p < PP_; ++p) {
        const float gx = 2.0f * lx[p] - 1.0f;
        const float gy = 2.0f * ly[p] - 1.0f;
        const float xp = ((gx + 1.0f) * (float)HW_ - 1.0f) * 0.5f;
        const float yp = ((gy + 1.0f) * (float)HW_ - 1.0f) * 0.5f;
        const float x0f = floorf(xp), y0f = floorf(yp);
        const float wx1 = xp - x0f, wy1 = yp - y0f;
        const float wx0 = 1.0f - wx1, wy0 = 1.0f - wy1;
        const int ix0 = (int)x0f, iy0 = (int)y0f;
#pragma unroll
        for (int k = 0; k < 4; ++k) {
            const int cx = ix0 + (k & 1);
            const int cy = iy0 + (k >> 1);
            const bool valid = (cx >= 0) & (cx < HW_) & (cy >= 0) & (cy < HW_);
            float w = ((k & 1) ? wx1 : wx0) * ((k >> 1) ? wy1 : wy0);
            wgt[p][k] = valid ? w : 0.0f;
            const int pix = min(max(cy, 0), HW_ - 1) * HW_ + min(max(cx, 0), HW_ - 1);
            eoff[p][k] = pix * 256;            // fp16 element offset within batch
        }
    }

    const _Float16* pb = packed + (size_t)b * ((size_t)NN_ * 256) + s * 8;

    // gather + packed-fp16 accumulate: fw[p] = [feat ch0..3 | wt ch0..3]
    f16x8 fw[PP_];
#pragma unroll
    for (int p = 0; p < PP_; ++p) {
        f16x8 a0 = *(const f16x8*)(pb + eoff[p][0]);
        f16x8 a1 = *(const f16x8*)(pb + eoff[p][1]);
        f16x8 a2 = *(const f16x8*)(pb + eoff[p][2]);
        f16x8 a3 = *(const f16x8*)(pb + eoff[p][3]);
        fw[p] = a0 * (_Float16)wgt[p][0] + a1 * (_Float16)wgt[p][1]
              + a2 * (_Float16)wgt[p][2] + a3 * (_Float16)wgt[p][3];
    }

    // combine in f32: acc_c += feat_c * (wt_c - dA_own_c)
    f32x4 acc;
    acc.x = acc.y = acc.z = acc.w = 0.0f;
    const float d0 = (float)own[4], d1 = (float)own[5];
    const float d2 = (float)own[6], d3 = (float)own[7];
#pragma unroll
    for (int p = 0; p < PP_; ++p) {
        acc.x = fmaf((float)fw[p][0], (float)fw[p][4] - d0, acc.x);
        acc.y = fmaf((float)fw[p][1], (float)fw[p][5] - d1, acc.y);
        acc.z = fmaf((float)fw[p][2], (float)fw[p][6] - d2, acc.z);
        acc.w = fmaf((float)fw[p][3], (float)fw[p][7] - d3, acc.w);
    }

    f32x4 res;
    res.x = acc.x * 0.25f;
    res.y = acc.y * 0.25f;
    res.z = acc.z * 0.25f;
    res.w = acc.w * 0.25f;
    __builtin_nontemporal_store(res, (f32x4*)(out + rowstart + s * 4));
}

// ---- Fallback: fused f32 kernel (known-good) if ws too small ---------------
__global__ __launch_bounds__(256) void sao_fused(
    const float* __restrict__ x,
    const float* __restrict__ dA,
    const float* __restrict__ Wo,
    const float* __restrict__ bo,
    float* __restrict__ out,
    float* __restrict__ locs)
{
    const int lane = threadIdx.x & 63;
    const int h = lane >> 5;
    const int s = lane & 31;
    const int wv = threadIdx.x >> 6;
    const int nblk = gridDim.x;
    const int q = nblk >> 3, r = nblk & 7;
    const int xcd = blockIdx.x & 7;
    const int work = (xcd < r ? xcd * (q + 1) : r * (q + 1) + (xcd - r) * q)
                     + (blockIdx.x >> 3);
    const int pt = work * 8 + wv * 2 + h;
    const int b = pt >> 14;
    const int n = pt & (NN_ - 1);
    const int ix = n & (HW_ - 1);
    const int iy = n >> 7;
    const size_t rowstart = (size_t)pt * CC_;
    const float4 d4 = *(const float4*)(dA + rowstart + s * 4);
    const int o = s & 7;
    const int chunk = s >> 3;
    const float* xr = x + rowstart + chunk * 32;
    const float* wr = Wo + o * CC_ + chunk * 32;
    float partial = 0.0f;
#pragma unroll
    for (int j = 0; j < 8; ++j) {
        const float4 xv = *(const float4*)(xr + 4 * j);
        const float4 wvv = *(const float4*)(wr + 4 * j);
        partial += xv.x * wvv.x + xv.y * wvv.y + xv.z * wvv.z + xv.w * wvv.w;
    }
    partial += __shfl_xor(partial, 8);
    partial += __shfl_xor(partial, 16);
    const float offv = partial + bo[o];
    const float refx = (ix + 0.5f) * (1.0f / HW_);
    const float refy = (iy + 0.5f) * (1.0f / HW_);
    if (s < 8) {
        const float ref = (o & 1) ? refy : refx;
        locs[(size_t)pt * 8 + o] = ref + offv * (1.0f / HW_);
    }
    float offs[8];
#pragma unroll
    for (int oo = 0; oo < 8; ++oo)
        offs[oo] = __shfl(offv, oo, 32);
    const size_t bbase = (size_t)b * (size_t)(NN_ * CC_) + s * 4;
    float4 acc = make_float4(0.f, 0.f, 0.f, 0.f);
#pragma unroll
    for (int p = 0; p < PP_; ++p) {
        const float locx = refx + offs[2 * p] * (1.0f / HW_);
        const float locy = refy + offs[2 * p + 1] * (1.0f / HW_);
        const float gx = 2.0f * locx - 1.0f;
        const float gy = 2.0f * locy - 1.0f;
        const float xp = ((gx + 1.0f) * (float)HW_ - 1.0f) * 0.5f;
        const float yp = ((gy + 1.0f) * (float)HW_ - 1.0f) * 0.5f;
        const float x0f = floorf(xp), y0f = floorf(yp);
        const float wx1 = xp - x0f, wy1 = yp - y0f;
        const float wx0 = 1.0f - wx1, wy0 = 1.0f - wy1;
        const int ix0 = (int)x0f, iy0 = (int)y0f;
        float4 feat = make_float4(0.f, 0.f, 0.f, 0.f);
        float4 wt = make_float4(0.f, 0.f, 0.f, 0.f);
#pragma unroll
        for (int k = 0; k < 4; ++k) {
            const int cx = ix0 + (k & 1);
            const int cy = iy0 + (k >> 1);
            const bool valid = (cx >= 0) & (cx < HW_) & (cy >= 0) & (cy < HW_);
            float w = ((k & 1) ? wx1 : wx0) * ((k >> 1) ? wy1 : wy0);
            w = valid ? w : 0.0f;
            const int pix = min(max(cy, 0), HW_ - 1) * HW_ + min(max(cx, 0), HW_ - 1);
            const size_t cb = bbase + (size_t)pix * CC_;
            const float4 xv = *(const float4*)(x + cb);
            const float4 dv = *(const float4*)(dA + cb);
            feat.x = fmaf(w, xv.x, feat.x);
            feat.y = fmaf(w, xv.y, feat.y);
            feat.z = fmaf(w, xv.z, feat.z);
            feat.w = fmaf(w, xv.w, feat.w);
            wt.x = fmaf(w, dv.x, wt.x);
            wt.y = fmaf(w, dv.y, wt.y);
            wt.z = fmaf(w, dv.z, wt.z);
            wt.w = fmaf(w, dv.w, wt.w);
        }
        acc.x = fmaf(feat.x, wt.x - d4.x, acc.x);
        acc.y = fmaf(feat.y, wt.y - d4.y, acc.y);
        acc.z = fmaf(feat.z, wt.z - d4.z, acc.z);
        acc.w = fmaf(feat.w, wt.w - d4.w, acc.w);
    }
    f32x4 res;
    res.x = acc.x * 0.25f;
    res.y = acc.y * 0.25f;
    res.z = acc.z * 0.25f;
    res.w = acc.w * 0.25f;
    __builtin_nontemporal_store(res, (f32x4*)(out + rowstart + s * 4));
}

extern "C" void kernel_launch(void* const* d_in, const int* in_sizes, int n_in,
                              void* d_out, int out_size, void* d_ws, size_t ws_size,
                              hipStream_t stream) {
    const float* x = (const float*)d_in[0];
    const float* dA = (const float*)d_in[1];
    const float* Wo = (const float*)d_in[4];
    const float* bo = (const float*)d_in[5];
    float* out = (float*)d_out;

    const int points = in_sizes[0] / CC_;               // B*N = 65536
    float* locs = out + (size_t)points * CC_;           // second tuple output
    const int blocks = points / 8;

    const size_t need = (size_t)points * 256 * sizeof(_Float16);  // 32 MB
    if (ws_size >= need) {
        _Float16* packed = (_Float16*)d_ws;
        sao_pack<<<blocks, 256, 0, stream>>>(x, dA, Wo, bo, locs, packed);
        sao_gather<<<blocks, 256, 0, stream>>>(packed, locs, out);
    } else {
        sao_fused<<<blocks, 256, 0, stream>>>(x, dA, Wo, bo, out, locs);
    }
}